// Round 1
// 872.822 us; speedup vs baseline: 1.0542x; 1.0542x over previous
//
#include <hip/hip_runtime.h>
#include <cstdint>

// ---------------- problem constants ----------------
#define NB     2
#define SEQ    2048
#define DIMN   2048
#define NROWS  (NB*SEQ)        // 4096
#define NHEADS 32
#define DHEAD  64
#define FFN    8192
#define HC     10368           // used cols of h: 2048 q | 64 k | 64 v | 8192 ffn
#define WINLD  18560           // W_in full leading dim
#define OI     10240           // W_out rows (attn 2048 | ffn 8192)

typedef __bf16 bf16_t;
typedef bf16_t bf16x8 __attribute__((ext_vector_type(8)));
typedef bf16_t bf16x4 __attribute__((ext_vector_type(4)));
typedef bf16_t bf16x2 __attribute__((ext_vector_type(2)));
typedef float  f32x4  __attribute__((ext_vector_type(4)));

typedef const uint32_t __attribute__((address_space(1)))* as1p;
typedef uint32_t __attribute__((address_space(3)))* as3p;

// async global->LDS, 16B/lane. LDS dest = wave-uniform base + lane*16 (guide §5).
__device__ __forceinline__ void load_lds16(const void* g, void* l) {
  __builtin_amdgcn_global_load_lds(
      reinterpret_cast<as1p>(reinterpret_cast<uintptr_t>(g)),
      reinterpret_cast<as3p>(reinterpret_cast<uintptr_t>(l)),
      16, 0, 0);
}

// ---------------- 1. LayerNorm -> bf16 ----------------
__global__ __launch_bounds__(256) void ln_kernel(const float* __restrict__ x,
                                                 const float* __restrict__ gamma,
                                                 const float* __restrict__ beta,
                                                 bf16_t* __restrict__ xnb)
{
  const int row = blockIdx.x;
  const int t = threadIdx.x;
  const float4* xr = (const float4*)(x + (size_t)row * DIMN);
  float4 v0 = xr[t], v1 = xr[t + 256];
  float s  = v0.x+v0.y+v0.z+v0.w + v1.x+v1.y+v1.z+v1.w;
  float ss = v0.x*v0.x+v0.y*v0.y+v0.z*v0.z+v0.w*v0.w
           + v1.x*v1.x+v1.y*v1.y+v1.z*v1.z+v1.w*v1.w;
#pragma unroll
  for (int off = 32; off; off >>= 1) { s += __shfl_xor(s, off); ss += __shfl_xor(ss, off); }
  __shared__ float red[8];
  const int w = t >> 6;
  if ((t & 63) == 0) { red[w] = s; red[w + 4] = ss; }
  __syncthreads();
  s  = red[0]+red[1]+red[2]+red[3];
  ss = red[4]+red[5]+red[6]+red[7];
  const float mu   = s * (1.f/DIMN);
  const float var  = ss * (1.f/DIMN) - mu*mu;
  const float rstd = rsqrtf(var + 1e-5f);
  const float4* g4 = (const float4*)gamma;
  const float4* b4 = (const float4*)beta;
  float4 ga0 = g4[t], ga1 = g4[t+256], be0 = b4[t], be1 = b4[t+256];
  float4 y0, y1;
  y0.x = (v0.x-mu)*rstd*ga0.x + be0.x;  y0.y = (v0.y-mu)*rstd*ga0.y + be0.y;
  y0.z = (v0.z-mu)*rstd*ga0.z + be0.z;  y0.w = (v0.w-mu)*rstd*ga0.w + be0.w;
  y1.x = (v1.x-mu)*rstd*ga1.x + be1.x;  y1.y = (v1.y-mu)*rstd*ga1.y + be1.y;
  y1.z = (v1.z-mu)*rstd*ga1.z + be1.z;  y1.w = (v1.w-mu)*rstd*ga1.w + be1.w;
  bf16_t* xo = xnb + (size_t)row * DIMN;
  bf16x4 o0 = {(bf16_t)y0.x, (bf16_t)y0.y, (bf16_t)y0.z, (bf16_t)y0.w};
  bf16x4 o1 = {(bf16_t)y1.x, (bf16_t)y1.y, (bf16_t)y1.z, (bf16_t)y1.w};
  *(bf16x4*)(xo + t*4)        = o0;
  *(bf16x4*)(xo + (t+256)*4)  = o1;
}

// ---------------- 2. transpose-cast fp32 -> bf16 (out[r][c] = in[c][r]) ----------------
__global__ __launch_bounds__(256) void tcast_kernel(const float* __restrict__ in, int ld_in,
                                                    bf16_t* __restrict__ out, int out_cols)
{
  __shared__ float tile[128][33];
  const int t = threadIdx.x;
  const int ic0 = blockIdx.x * 32;    // in col block = out row block
  const int ir0 = blockIdx.y * 128;   // in row block = out col block
#pragma unroll
  for (int k = 0; k < 16; k++) {
    const int idx = k*256 + t, row = idx >> 5, col = idx & 31;
    tile[row][col] = in[(size_t)(ir0 + row) * ld_in + ic0 + col];
  }
  __syncthreads();
#pragma unroll
  for (int k = 0; k < 8; k++) {
    const int idx = k*256 + t, r = idx >> 6, cp = idx & 63;
    bf16x2 v = {(bf16_t)tile[cp*2][r], (bf16_t)tile[cp*2 + 1][r]};
    *(bf16x2*)&out[(size_t)(ic0 + r) * out_cols + ir0 + cp*2] = v;
  }
}

// ---------------- 3. 8-phase 256-class GEMM (guide §5 template, plain HIP) ----------------
// BMxBN tile, BK=64, 512 thr = 8 waves (2M x 4N). Quadrant-per-phase schedule:
// phase (qm,qn) reads only A-half qm + B-half qn, so each staging call targets a
// half last read two barriers earlier. Counted vmcnt (T4), st-swizzle (T2), setprio (T5).
// OP=0: C bf16 (ld HC), A=xnb.  OP=1: C f32 + Res, A = [Attn | H+2176] concat at k=2048.
#define BW_NONE ((void)0)
#define BW_VM   asm volatile("s_waitcnt vmcnt(%0)" :: "n"(VM))
#define BW_V0   asm volatile("s_waitcnt vmcnt(0)")

template<int BM, int BN, int KTOT, int OP>
__global__ __launch_bounds__(512, 2) void gemm8p(
    const bf16_t* __restrict__ A0p, const bf16_t* __restrict__ A1p,
    const bf16_t* __restrict__ Btp, const bf16_t* __restrict__ Res,
    bf16_t* __restrict__ Cb, float* __restrict__ Cf)
{
  constexpr int NT    = KTOT / 64;       // K tiles
  constexpr int NP    = NT / 2;          // tile pairs
  constexpr int MR    = BM / 64;         // m-frags per phase per wave
  constexpr int NRr   = BN / 128;        // n-frags per phase per wave
  constexpr int ALPT  = BM / 128;        // A loads/thread per half-tile
  constexpr int BLPT  = BN / 128;
  constexpr int VM    = ALPT + BLPT;     // steady-state vmcnt
  constexpr int AHALF = (BM/2)*64;       // elements
  constexpr int BHALF = (BN/2)*64;
  constexpr int ABUF  = BM*64;
  constexpr int BUFSZ = ABUF + BN*64;
  constexpr int BLD   = OP ? OI : DIMN;
  constexpr int CPX   = OP ? 32 : 82;    // grid/8 for XCD swizzle
  __shared__ __align__(16) bf16_t lds[2*BUFSZ];

  const int t = threadIdx.x;
  const int l = t & 63, w = t >> 6;
  const int wm2 = w >> 2, wn2 = w & 3;
  const int lr = l & 15, lq = l >> 4;

  const int id  = blockIdx.x;
  const int swz = (id & 7) * CPX + (id >> 3);
  int m0, n0;
  if (OP == 0) {                       // 16 m-tiles x 41 n-tiles (last clamped: overlap
    m0 = (swz & 15) << 8;              //  region recomputed identically by 2 blocks)
    n0 = (swz >> 4) << 8;
    if (n0 > HC - 256) n0 = HC - 256;
  } else {                             // 32 m-tiles x 8 n-tiles
    m0 = (swz & 31) << 7;
    n0 = (swz >> 5) << 8;
  }

  // staging source pre-swizzle (rule 21: linear LDS dest, inverse-swz global src)
  const int rsw = (w << 3) | (l >> 3);                    // row within 64-row call
  const int csw = (((l & 7) ^ ((l >> 3) & 7)) << 3);      // element col offset
  // read-side swizzled chunk offsets for kk=0,1 (chunk ^= row&7, row&7 == lr&7)
  const int axor[2] = { ((lq ^ (lr & 7)) << 3), (((4 + lq) ^ (lr & 7)) << 3) };
  const int arow = wm2*(BM/4) + lr;
  const int brow = wn2*(BN/8) + lr;

  auto stA = [&](int buf, int half, int kt) {
    const int k0 = kt * 64;
#pragma unroll
    for (int c = 0; c < ALPT; c++) {
      const int gr = m0 + half*(BM/2) + c*64 + rsw;
      const bf16_t* src;
      if (OP == 0 || k0 < DIMN) src = A0p + (size_t)gr * DIMN + k0 + csw;
      else                      src = A1p + (size_t)gr * HC + 2176 + (k0 - DIMN) + csw;
      load_lds16(src, lds + buf*BUFSZ + half*AHALF + c*4096 + (w << 9));
    }
  };
  auto stB = [&](int buf, int half, int kt) {
    const int k0 = kt * 64;
#pragma unroll
    for (int c = 0; c < BLPT; c++) {
      const int gr = n0 + half*(BN/2) + c*64 + rsw;
      load_lds16(Btp + (size_t)gr * BLD + k0 + csw,
                 lds + buf*BUFSZ + ABUF + half*BHALF + c*4096 + (w << 9));
    }
  };

  f32x4 acc[2][2][MR][NRr];
  const f32x4 z4 = {0.f,0.f,0.f,0.f};
#pragma unroll
  for (int qm = 0; qm < 2; qm++)
#pragma unroll
    for (int qn = 0; qn < 2; qn++)
#pragma unroll
      for (int i = 0; i < MR; i++)
#pragma unroll
        for (int j = 0; j < NRr; j++) acc[qm][qn][i][j] = z4;

  // prologue: all of tile0 (buf0) + A0,B0 of tile1 (buf1); wait leaves those 2 in flight
  stA(0,0,0); stA(0,1,0); stB(0,0,0); stB(0,1,0);
  stA(1,0,1); stB(1,0,1);
  BW_VM;
  __builtin_amdgcn_sched_barrier(0);
  __builtin_amdgcn_s_barrier();
  __builtin_amdgcn_sched_barrier(0);

#define PHASE(BUF, QM, QN, STAGE, BWAIT)                                      \
  {                                                                           \
    bf16x8 af[MR][2], bfr[NRr][2];                                            \
    _Pragma("unroll")                                                         \
    for (int i_ = 0; i_ < MR; i_++)                                           \
      _Pragma("unroll")                                                       \
      for (int kk_ = 0; kk_ < 2; kk_++)                                       \
        af[i_][kk_] = *(const bf16x8*)&lds[(BUF)*BUFSZ + (QM)*AHALF           \
                        + (arow + i_*16)*64 + axor[kk_]];                     \
    _Pragma("unroll")                                                         \
    for (int j_ = 0; j_ < NRr; j_++)                                          \
      _Pragma("unroll")                                                       \
      for (int kk_ = 0; kk_ < 2; kk_++)                                       \
        bfr[j_][kk_] = *(const bf16x8*)&lds[(BUF)*BUFSZ + ABUF + (QN)*BHALF   \
                        + (brow + j_*16)*64 + axor[kk_]];                     \
    STAGE;                                                                    \
    __builtin_amdgcn_s_barrier();                                             \
    __builtin_amdgcn_sched_barrier(0);                                        \
    __builtin_amdgcn_s_setprio(1);                                            \
    _Pragma("unroll")                                                         \
    for (int i_ = 0; i_ < MR; i_++)                                           \
      _Pragma("unroll")                                                       \
      for (int j_ = 0; j_ < NRr; j_++)                                        \
        _Pragma("unroll")                                                     \
        for (int kk_ = 0; kk_ < 2; kk_++)                                     \
          acc[QM][QN][i_][j_] = __builtin_amdgcn_mfma_f32_16x16x32_bf16(      \
              af[i_][kk_], bfr[j_][kk_], acc[QM][QN][i_][j_], 0, 0, 0);       \
    __builtin_amdgcn_s_setprio(0);                                            \
    BWAIT;                                                                    \
    __builtin_amdgcn_s_barrier();                                             \
    __builtin_amdgcn_sched_barrier(0);                                        \
  }

  // steady pairs: tiles e=2i (buf0), o=2i+1 (buf1); staging always lands in a half
  // whose last reader finished at the previous phase's trailing barrier.
  for (int it = 0; it < NP-1; it++) {
    const int e = 2*it, o = e+1;
    PHASE(0,0,0, stA(1,1,o),   BW_NONE)
    PHASE(0,0,1, stB(1,1,o),   BW_NONE)
    PHASE(0,1,0, stA(0,0,e+2), BW_NONE)
    PHASE(0,1,1, stB(0,0,e+2), BW_VM)     // tile o fully landed here
    PHASE(1,0,0, stA(0,1,e+2), BW_NONE)
    PHASE(1,0,1, stB(0,1,e+2), BW_NONE)
    PHASE(1,1,0, stA(1,0,o+2), BW_NONE)
    PHASE(1,1,1, stB(1,0,o+2), BW_VM)     // tile e+2 fully landed here
  }
  { // peeled last pair (tiles NT-2 / NT-1): finish staging, drain, no overrun
    const int o = NT-1;
    PHASE(0,0,0, stA(1,1,o), BW_NONE)
    PHASE(0,0,1, stB(1,1,o), BW_NONE)
    PHASE(0,1,0, BW_NONE,    BW_NONE)
    PHASE(0,1,1, BW_NONE,    BW_V0)       // drain: last tile fully landed
    PHASE(1,0,0, BW_NONE,    BW_NONE)
    PHASE(1,0,1, BW_NONE,    BW_NONE)
    PHASE(1,1,0, BW_NONE,    BW_NONE)
    PHASE(1,1,1, BW_NONE,    BW_NONE)
  }
#undef PHASE

  // epilogue: C/D layout col=lane&15, row=(lane>>4)*4+r (guide §3)
#pragma unroll
  for (int qm = 0; qm < 2; qm++)
#pragma unroll
    for (int qn = 0; qn < 2; qn++)
#pragma unroll
      for (int i = 0; i < MR; i++)
#pragma unroll
        for (int j = 0; j < NRr; j++) {
          const int row = m0 + qm*(BM/2) + wm2*(BM/4) + i*16 + lq*4;
          const int col = n0 + qn*(BN/2) + wn2*(BN/8) + j*16 + lr;
#pragma unroll
          for (int r = 0; r < 4; r++) {
            if (OP == 0) {
              Cb[(size_t)(row + r) * HC + col] = (bf16_t)acc[qm][qn][i][j][r];
            } else {
              const size_t idx = (size_t)(row + r) * DIMN + col;
              Cf[idx] = acc[qm][qn][i][j][r] + (float)Res[idx];
            }
          }
        }
}

// ---------------- 4. RoPE in-place on q,k of h; extract V^T ----------------
__global__ __launch_bounds__(256) void rope_kernel(bf16_t* __restrict__ H, bf16_t* __restrict__ Vt)
{
  const int row = blockIdx.x;          // b*SEQ + s
  const int s = row & (SEQ - 1);
  const int b = row >> 11;
  bf16_t* hr = H + (size_t)row * HC;
  const int t = threadIdx.x;
  for (int task = t; task < 1056; task += 256) {
    const int hd = task >> 5, j = task & 31;
    const int base = (hd < 32) ? hd*64 : 2048;
    const float inv = exp2f(-(float)j * 0.41524101186092437f);
    const float ang = (float)s * inv;
    float sn, cs;
    sincosf(ang, &sn, &cs);
    const float x1 = (float)hr[base + j], x2 = (float)hr[base + j + 32];
    const float sc = (hd < 32) ? 0.125f : 1.0f;   // SCALE on q only
    hr[base + j]      = (bf16_t)((x1*cs - x2*sn) * sc);
    hr[base + j + 32] = (bf16_t)((x2*cs + x1*sn) * sc);
  }
  for (int d = t; d < 64; d += 256)
    Vt[(size_t)(b*64 + d) * SEQ + s] = hr[2112 + d];
}

// ---------------- 5. flash attention (causal, MQA) ----------------
template<int NTMAX, bool MASK>
__device__ __forceinline__ void attn_tile_body(
    const bf16_t* __restrict__ Qs, const bf16_t* __restrict__ Ks,
    const bf16_t* __restrict__ Vts, bf16_t* __restrict__ Ps,
    f32x4 (&accO)[4], float (&m_run)[4], float (&l_run)[4],
    int w, int lr, int lq, int q0, int j0)
{
  const f32x4 z4 = {0.f,0.f,0.f,0.f};
  f32x4 accS[NTMAX];
#pragma unroll
  for (int i = 0; i < NTMAX; i++) accS[i] = z4;
  bf16x8 aq[2];
#pragma unroll
  for (int kt = 0; kt < 2; kt++)
    aq[kt] = *(const bf16x8*)&Qs[(w*16 + lr)*72 + kt*32 + lq*8];
#pragma unroll
  for (int nt = 0; nt < NTMAX; nt++)
#pragma unroll
    for (int kt = 0; kt < 2; kt++) {
      bf16x8 bk = *(const bf16x8*)&Ks[(nt*16 + lr)*72 + kt*32 + lq*8];
      accS[nt] = __builtin_amdgcn_mfma_f32_16x16x32_bf16(aq[kt], bk, accS[nt], 0, 0, 0);
    }
  if (MASK) {
    const int rg0 = q0 + w*16 + lq*4;
#pragma unroll
    for (int nt = 0; nt < NTMAX; nt++) {
      const int cg = j0 + nt*16 + lr;
#pragma unroll
      for (int r = 0; r < 4; r++)
        if (cg > rg0 + r) accS[nt][r] = -3.0e38f;
    }
  }
  float al[4];
#pragma unroll
  for (int r = 0; r < 4; r++) {
    float m = accS[0][r];
#pragma unroll
    for (int nt = 1; nt < NTMAX; nt++) m = fmaxf(m, accS[nt][r]);
    m = fmaxf(m, __shfl_xor(m, 1)); m = fmaxf(m, __shfl_xor(m, 2));
    m = fmaxf(m, __shfl_xor(m, 4)); m = fmaxf(m, __shfl_xor(m, 8));
    const float nm = fmaxf(m_run[r], m);
    al[r] = __expf(m_run[r] - nm);
    m_run[r] = nm;
  }
#pragma unroll
  for (int nt = 0; nt < NTMAX; nt++)
#pragma unroll
    for (int r = 0; r < 4; r++)
      accS[nt][r] = __expf(accS[nt][r] - m_run[r]);
#pragma unroll
  for (int r = 0; r < 4; r++) {
    float sum = 0.f;
#pragma unroll
    for (int nt = 0; nt < NTMAX; nt++) sum += accS[nt][r];
    sum += __shfl_xor(sum, 1); sum += __shfl_xor(sum, 2);
    sum += __shfl_xor(sum, 4); sum += __shfl_xor(sum, 8);
    l_run[r] = l_run[r]*al[r] + sum;
  }
#pragma unroll
  for (int nt = 0; nt < 4; nt++)
#pragma unroll
    for (int r = 0; r < 4; r++) accO[nt][r] *= al[r];
#pragma unroll
  for (int nt = 0; nt < NTMAX; nt++)
#pragma unroll
    for (int r = 0; r < 4; r++)
      Ps[(w*16 + lq*4 + r)*136 + nt*16 + lr] = (bf16_t)accS[nt][r];
  __syncthreads();   // block-uniform call site
#pragma unroll
  for (int kt = 0; kt < NTMAX/2; kt++) {
    bf16x8 ap = *(const bf16x8*)&Ps[(w*16 + lr)*136 + kt*32 + lq*8];
#pragma unroll
    for (int nt = 0; nt < 4; nt++) {
      bf16x8 bv = *(const bf16x8*)&Vts[(nt*16 + lr)*136 + kt*32 + lq*8];
      accO[nt] = __builtin_amdgcn_mfma_f32_16x16x32_bf16(ap, bv, accO[nt], 0, 0, 0);
    }
  }
}

__global__ __launch_bounds__(256, 2) void attn_kernel(const bf16_t* __restrict__ H,
                                                      const bf16_t* __restrict__ Vt,
                                                      bf16_t* __restrict__ AttnOut)
{
  __shared__ __align__(16) bf16_t Qs[64*72];
  __shared__ __align__(16) bf16_t Ks[128*72];
  __shared__ __align__(16) bf16_t Vts[64*136];
  __shared__ __align__(16) bf16_t Ps[64*136];
  const int t = threadIdx.x, l = t & 63, w = t >> 6, lr = l & 15, lq = l >> 4;
  const int qb = blockIdx.x, head = blockIdx.y, b = blockIdx.z;
  const int q0 = qb * 64;
  const size_t hbase = (size_t)(b * SEQ) * HC;

#pragma unroll
  for (int i = 0; i < 2; i++) {
    const int id = t + i*256, row = id >> 3, ch = (id & 7) << 3;
    bf16x8 v = *(const bf16x8*)&H[hbase + (size_t)(q0 + row) * HC + head*64 + ch];
    *(bf16x8*)&Qs[row*72 + ch] = v;
  }
  f32x4 accO[4];
  const f32x4 z4 = {0.f,0.f,0.f,0.f};
#pragma unroll
  for (int i = 0; i < 4; i++) accO[i] = z4;
  float m_run[4], l_run[4];
#pragma unroll
  for (int r = 0; r < 4; r++) { m_run[r] = -3.0e38f; l_run[r] = 0.f; }
  const int ntiles = (qb >> 1) + 1;
  __syncthreads();

  for (int tile = 0; tile < ntiles; tile++) {
    const int j0 = tile * 128;
#pragma unroll
    for (int i = 0; i < 4; i++) {
      const int id = t + i*256, row = id >> 3, ch = (id & 7) << 3;
      bf16x8 v = *(const bf16x8*)&H[hbase + (size_t)(j0 + row) * HC + 2048 + ch];
      *(bf16x8*)&Ks[row*72 + ch] = v;
    }
#pragma unroll
    for (int i = 0; i < 4; i++) {
      const int id = t + i*256, row = id >> 4, ch = (id & 15) << 3;
      bf16x8 v = *(const bf16x8*)&Vt[(size_t)(b*64 + row) * SEQ + j0 + ch];
      *(bf16x8*)&Vts[row*136 + ch] = v;
    }
    __syncthreads();
    if (tile < ntiles - 1)
      attn_tile_body<8,false>(Qs, Ks, Vts, Ps, accO, m_run, l_run, w, lr, lq, q0, j0);
    else if ((qb & 1) == 0)
      attn_tile_body<4,true >(Qs, Ks, Vts, Ps, accO, m_run, l_run, w, lr, lq, q0, j0);
    else
      attn_tile_body<8,true >(Qs, Ks, Vts, Ps, accO, m_run, l_run, w, lr, lq, q0, j0);
    __syncthreads();
  }
  float inv_l[4];
#pragma unroll
  for (int r = 0; r < 4; r++) inv_l[r] = 1.f / l_run[r];
#pragma unroll
  for (int nt = 0; nt < 4; nt++)
#pragma unroll
    for (int r = 0; r < 4; r++)
      AttnOut[(size_t)(b*SEQ + q0 + w*16 + lq*4 + r) * DIMN + head*64 + nt*16 + lr]
          = (bf16_t)(accO[nt][r] * inv_l[r]);
}

// ---------------- launcher ----------------
extern "C" void kernel_launch(void* const* d_in, const int* in_sizes, int n_in,
                              void* d_out, int out_size, void* d_ws, size_t ws_size,
                              hipStream_t stream)
{
  const float* x     = (const float*)d_in[0];
  const float* W_in  = (const float*)d_in[1];
  const float* W_out = (const float*)d_in[2];
  const float* gamma = (const float*)d_in[3];
  const float* beta  = (const float*)d_in[4];
  float* out = (float*)d_out;

  char* ws = (char*)d_ws;
  bf16_t* xnb   = (bf16_t*)(ws);                 // 16,777,216
  bf16_t* h     = (bf16_t*)(ws + 16777216);      // 84,934,656
  bf16_t* WinT  = (bf16_t*)(ws + 101711872);     // 42,467,328  [HC][DIMN]
  bf16_t* WoutT = (bf16_t*)(ws + 144179200);     // 41,943,040  [DIMN][OI]
  bf16_t* Vt    = (bf16_t*)(ws + 186122240);     //    524,288  [NB][64][SEQ]
  bf16_t* attn  = (bf16_t*)(ws + 186646528);     // 16,777,216  [NROWS][DIMN]

  ln_kernel<<<NROWS, 256, 0, stream>>>(x, gamma, beta, xnb);
  tcast_kernel<<<dim3(HC/32, DIMN/128), 256, 0, stream>>>(W_in, WINLD, WinT, DIMN);
  tcast_kernel<<<dim3(DIMN/32, OI/128), 256, 0, stream>>>(W_out, DIMN, WoutT, OI);
  // GEMM1: 16 m x 41 n (last n-tile clamped/overlapping), 656 = 8*82 -> XCD swizzle
  gemm8p<256,256,DIMN,0><<<656, 512, 0, stream>>>(xnb, nullptr, WinT, nullptr, h, nullptr);
  rope_kernel<<<NROWS, 256, 0, stream>>>(h, Vt);
  attn_kernel<<<dim3(SEQ/64, NHEADS, NB), 256, 0, stream>>>(h, Vt, attn);
  // GEMM2: 32 m x 8 n = 256 blocks (exactly 1/CU at 96KiB LDS)
  gemm8p<128,256,OI,1><<<256, 512, 0, stream>>>(attn, h, WoutT, xnb, nullptr, out);
}

// Round 2
// 797.280 us; speedup vs baseline: 1.1540x; 1.0948x over previous
//
#include <hip/hip_runtime.h>
#include <cstdint>

// ---------------- problem constants ----------------
#define NB     2
#define SEQ    2048
#define DIMN   2048
#define NROWS  (NB*SEQ)        // 4096
#define NHEADS 32
#define DHEAD  64
#define FFN    8192
#define HC     10368           // used cols of h: 2048 q | 64 k | 64 v | 8192 ffn
#define WINLD  18560           // W_in full leading dim
#define OI     10240           // W_out rows (attn 2048 | ffn 8192)

typedef __bf16 bf16_t;
typedef bf16_t bf16x8 __attribute__((ext_vector_type(8)));
typedef bf16_t bf16x4 __attribute__((ext_vector_type(4)));
typedef bf16_t bf16x2 __attribute__((ext_vector_type(2)));
typedef float  f32x4  __attribute__((ext_vector_type(4)));

typedef const uint32_t __attribute__((address_space(1)))* as1p;
typedef uint32_t __attribute__((address_space(3)))* as3p;

// async global->LDS, 16B/lane. LDS dest = wave-uniform base + lane*16 (guide §5).
__device__ __forceinline__ void load_lds16(const void* g, void* l) {
  __builtin_amdgcn_global_load_lds(
      reinterpret_cast<as1p>(reinterpret_cast<uintptr_t>(g)),
      reinterpret_cast<as3p>(reinterpret_cast<uintptr_t>(l)),
      16, 0, 0);
}

// ---------------- 1. LayerNorm -> bf16 ----------------
__global__ __launch_bounds__(256) void ln_kernel(const float* __restrict__ x,
                                                 const float* __restrict__ gamma,
                                                 const float* __restrict__ beta,
                                                 bf16_t* __restrict__ xnb)
{
  const int row = blockIdx.x;
  const int t = threadIdx.x;
  const float4* xr = (const float4*)(x + (size_t)row * DIMN);
  float4 v0 = xr[t], v1 = xr[t + 256];
  float s  = v0.x+v0.y+v0.z+v0.w + v1.x+v1.y+v1.z+v1.w;
  float ss = v0.x*v0.x+v0.y*v0.y+v0.z*v0.z+v0.w*v0.w
           + v1.x*v1.x+v1.y*v1.y+v1.z*v1.z+v1.w*v1.w;
#pragma unroll
  for (int off = 32; off; off >>= 1) { s += __shfl_xor(s, off); ss += __shfl_xor(ss, off); }
  __shared__ float red[8];
  const int w = t >> 6;
  if ((t & 63) == 0) { red[w] = s; red[w + 4] = ss; }
  __syncthreads();
  s  = red[0]+red[1]+red[2]+red[3];
  ss = red[4]+red[5]+red[6]+red[7];
  const float mu   = s * (1.f/DIMN);
  const float var  = ss * (1.f/DIMN) - mu*mu;
  const float rstd = rsqrtf(var + 1e-5f);
  const float4* g4 = (const float4*)gamma;
  const float4* b4 = (const float4*)beta;
  float4 ga0 = g4[t], ga1 = g4[t+256], be0 = b4[t], be1 = b4[t+256];
  float4 y0, y1;
  y0.x = (v0.x-mu)*rstd*ga0.x + be0.x;  y0.y = (v0.y-mu)*rstd*ga0.y + be0.y;
  y0.z = (v0.z-mu)*rstd*ga0.z + be0.z;  y0.w = (v0.w-mu)*rstd*ga0.w + be0.w;
  y1.x = (v1.x-mu)*rstd*ga1.x + be1.x;  y1.y = (v1.y-mu)*rstd*ga1.y + be1.y;
  y1.z = (v1.z-mu)*rstd*ga1.z + be1.z;  y1.w = (v1.w-mu)*rstd*ga1.w + be1.w;
  bf16_t* xo = xnb + (size_t)row * DIMN;
  bf16x4 o0 = {(bf16_t)y0.x, (bf16_t)y0.y, (bf16_t)y0.z, (bf16_t)y0.w};
  bf16x4 o1 = {(bf16_t)y1.x, (bf16_t)y1.y, (bf16_t)y1.z, (bf16_t)y1.w};
  *(bf16x4*)(xo + t*4)        = o0;
  *(bf16x4*)(xo + (t+256)*4)  = o1;
}

// ---------------- 2. transpose-cast fp32 -> bf16 (out[r][c] = in[c][r]) ----------------
__global__ __launch_bounds__(256) void tcast_kernel(const float* __restrict__ in, int ld_in,
                                                    bf16_t* __restrict__ out, int out_cols)
{
  __shared__ float tile[128][33];
  const int t = threadIdx.x;
  const int ic0 = blockIdx.x * 32;    // in col block = out row block
  const int ir0 = blockIdx.y * 128;   // in row block = out col block
#pragma unroll
  for (int k = 0; k < 16; k++) {
    const int idx = k*256 + t, row = idx >> 5, col = idx & 31;
    tile[row][col] = in[(size_t)(ir0 + row) * ld_in + ic0 + col];
  }
  __syncthreads();
#pragma unroll
  for (int k = 0; k < 8; k++) {
    const int idx = k*256 + t, r = idx >> 6, cp = idx & 63;
    bf16x2 v = {(bf16_t)tile[cp*2][r], (bf16_t)tile[cp*2 + 1][r]};
    *(bf16x2*)&out[(size_t)(ic0 + r) * out_cols + ir0 + cp*2] = v;
  }
}

// ---------------- 3. 8-phase 256-class GEMM (guide §5 template, plain HIP) ----------------
#define BW_NONE ((void)0)
#define BW_VM   asm volatile("s_waitcnt vmcnt(%0)" :: "n"(VM))
#define BW_V0   asm volatile("s_waitcnt vmcnt(0)")

template<int BM, int BN, int KTOT, int OP>
__global__ __launch_bounds__(512, 2) void gemm8p(
    const bf16_t* __restrict__ A0p, const bf16_t* __restrict__ A1p,
    const bf16_t* __restrict__ Btp, const bf16_t* __restrict__ Res,
    bf16_t* __restrict__ Cb, float* __restrict__ Cf)
{
  constexpr int NT    = KTOT / 64;       // K tiles
  constexpr int NP    = NT / 2;          // tile pairs
  constexpr int MR    = BM / 64;         // m-frags per phase per wave
  constexpr int NRr   = BN / 128;        // n-frags per phase per wave
  constexpr int ALPT  = BM / 128;        // A loads/thread per half-tile
  constexpr int BLPT  = BN / 128;
  constexpr int VM    = ALPT + BLPT;     // steady-state vmcnt
  constexpr int AHALF = (BM/2)*64;       // elements
  constexpr int BHALF = (BN/2)*64;
  constexpr int ABUF  = BM*64;
  constexpr int BUFSZ = ABUF + BN*64;
  constexpr int BLD   = OP ? OI : DIMN;
  constexpr int CPX   = OP ? 32 : 82;    // grid/8 for XCD swizzle
  __shared__ __align__(16) bf16_t lds[2*BUFSZ];

  const int t = threadIdx.x;
  const int l = t & 63, w = t >> 6;
  const int wm2 = w >> 2, wn2 = w & 3;
  const int lr = l & 15, lq = l >> 4;

  const int id  = blockIdx.x;
  const int swz = (id & 7) * CPX + (id >> 3);
  int m0, n0;
  if (OP == 0) {                       // 16 m-tiles x 41 n-tiles (last clamped)
    m0 = (swz & 15) << 8;
    n0 = (swz >> 4) << 8;
    if (n0 > HC - 256) n0 = HC - 256;
  } else {                             // 32 m-tiles x 8 n-tiles
    m0 = (swz & 31) << 7;
    n0 = (swz >> 5) << 8;
  }

  const int rsw = (w << 3) | (l >> 3);
  const int csw = (((l & 7) ^ ((l >> 3) & 7)) << 3);
  const int axor[2] = { ((lq ^ (lr & 7)) << 3), (((4 + lq) ^ (lr & 7)) << 3) };
  const int arow = wm2*(BM/4) + lr;
  const int brow = wn2*(BN/8) + lr;

  auto stA = [&](int buf, int half, int kt) {
    const int k0 = kt * 64;
#pragma unroll
    for (int c = 0; c < ALPT; c++) {
      const int gr = m0 + half*(BM/2) + c*64 + rsw;
      const bf16_t* src;
      if (OP == 0 || k0 < DIMN) src = A0p + (size_t)gr * DIMN + k0 + csw;
      else                      src = A1p + (size_t)gr * HC + 2176 + (k0 - DIMN) + csw;
      load_lds16(src, lds + buf*BUFSZ + half*AHALF + c*4096 + (w << 9));
    }
  };
  auto stB = [&](int buf, int half, int kt) {
    const int k0 = kt * 64;
#pragma unroll
    for (int c = 0; c < BLPT; c++) {
      const int gr = n0 + half*(BN/2) + c*64 + rsw;
      load_lds16(Btp + (size_t)gr * BLD + k0 + csw,
                 lds + buf*BUFSZ + ABUF + half*BHALF + c*4096 + (w << 9));
    }
  };

  f32x4 acc[2][2][MR][NRr];
  const f32x4 z4 = {0.f,0.f,0.f,0.f};
#pragma unroll
  for (int qm = 0; qm < 2; qm++)
#pragma unroll
    for (int qn = 0; qn < 2; qn++)
#pragma unroll
      for (int i = 0; i < MR; i++)
#pragma unroll
        for (int j = 0; j < NRr; j++) acc[qm][qn][i][j] = z4;

  stA(0,0,0); stA(0,1,0); stB(0,0,0); stB(0,1,0);
  stA(1,0,1); stB(1,0,1);
  BW_VM;
  __builtin_amdgcn_sched_barrier(0);
  __builtin_amdgcn_s_barrier();
  __builtin_amdgcn_sched_barrier(0);

#define PHASE(BUF, QM, QN, STAGE, BWAIT)                                      \
  {                                                                           \
    bf16x8 af[MR][2], bfr[NRr][2];                                            \
    _Pragma("unroll")                                                         \
    for (int i_ = 0; i_ < MR; i_++)                                           \
      _Pragma("unroll")                                                       \
      for (int kk_ = 0; kk_ < 2; kk_++)                                       \
        af[i_][kk_] = *(const bf16x8*)&lds[(BUF)*BUFSZ + (QM)*AHALF           \
                        + (arow + i_*16)*64 + axor[kk_]];                     \
    _Pragma("unroll")                                                         \
    for (int j_ = 0; j_ < NRr; j_++)                                          \
      _Pragma("unroll")                                                       \
      for (int kk_ = 0; kk_ < 2; kk_++)                                       \
        bfr[j_][kk_] = *(const bf16x8*)&lds[(BUF)*BUFSZ + ABUF + (QN)*BHALF   \
                        + (brow + j_*16)*64 + axor[kk_]];                     \
    STAGE;                                                                    \
    __builtin_amdgcn_s_barrier();                                             \
    __builtin_amdgcn_sched_barrier(0);                                        \
    __builtin_amdgcn_s_setprio(1);                                            \
    _Pragma("unroll")                                                         \
    for (int i_ = 0; i_ < MR; i_++)                                           \
      _Pragma("unroll")                                                       \
      for (int j_ = 0; j_ < NRr; j_++)                                        \
        _Pragma("unroll")                                                     \
        for (int kk_ = 0; kk_ < 2; kk_++)                                     \
          acc[QM][QN][i_][j_] = __builtin_amdgcn_mfma_f32_16x16x32_bf16(      \
              af[i_][kk_], bfr[j_][kk_], acc[QM][QN][i_][j_], 0, 0, 0);       \
    __builtin_amdgcn_s_setprio(0);                                            \
    BWAIT;                                                                    \
    __builtin_amdgcn_s_barrier();                                             \
    __builtin_amdgcn_sched_barrier(0);                                        \
  }

  for (int it = 0; it < NP-1; it++) {
    const int e = 2*it, o = e+1;
    PHASE(0,0,0, stA(1,1,o),   BW_NONE)
    PHASE(0,0,1, stB(1,1,o),   BW_NONE)
    PHASE(0,1,0, stA(0,0,e+2), BW_NONE)
    PHASE(0,1,1, stB(0,0,e+2), BW_VM)
    PHASE(1,0,0, stA(0,1,e+2), BW_NONE)
    PHASE(1,0,1, stB(0,1,e+2), BW_NONE)
    PHASE(1,1,0, stA(1,0,o+2), BW_NONE)
    PHASE(1,1,1, stB(1,0,o+2), BW_VM)
  }
  {
    const int o = NT-1;
    PHASE(0,0,0, stA(1,1,o), BW_NONE)
    PHASE(0,0,1, stB(1,1,o), BW_NONE)
    PHASE(0,1,0, BW_NONE,    BW_NONE)
    PHASE(0,1,1, BW_NONE,    BW_V0)
    PHASE(1,0,0, BW_NONE,    BW_NONE)
    PHASE(1,0,1, BW_NONE,    BW_NONE)
    PHASE(1,1,0, BW_NONE,    BW_NONE)
    PHASE(1,1,1, BW_NONE,    BW_NONE)
  }
#undef PHASE

#pragma unroll
  for (int qm = 0; qm < 2; qm++)
#pragma unroll
    for (int qn = 0; qn < 2; qn++)
#pragma unroll
      for (int i = 0; i < MR; i++)
#pragma unroll
        for (int j = 0; j < NRr; j++) {
          const int row = m0 + qm*(BM/2) + wm2*(BM/4) + i*16 + lq*4;
          const int col = n0 + qn*(BN/2) + wn2*(BN/8) + j*16 + lr;
#pragma unroll
          for (int r = 0; r < 4; r++) {
            if (OP == 0) {
              Cb[(size_t)(row + r) * HC + col] = (bf16_t)acc[qm][qn][i][j][r];
            } else {
              const size_t idx = (size_t)(row + r) * DIMN + col;
              Cf[idx] = acc[qm][qn][i][j][r] + (float)Res[idx];
            }
          }
        }
}

// ---------------- 4. RoPE in-place on q,k of h; extract V^T ----------------
__global__ __launch_bounds__(256) void rope_kernel(bf16_t* __restrict__ H, bf16_t* __restrict__ Vt)
{
  const int row = blockIdx.x;          // b*SEQ + s
  const int s = row & (SEQ - 1);
  const int b = row >> 11;
  bf16_t* hr = H + (size_t)row * HC;
  const int t = threadIdx.x;
  for (int task = t; task < 1056; task += 256) {
    const int hd = task >> 5, j = task & 31;
    const int base = (hd < 32) ? hd*64 : 2048;
    const float inv = exp2f(-(float)j * 0.41524101186092437f);
    const float ang = (float)s * inv;
    float sn, cs;
    sincosf(ang, &sn, &cs);
    const float x1 = (float)hr[base + j], x2 = (float)hr[base + j + 32];
    const float sc = (hd < 32) ? 0.125f : 1.0f;   // SCALE on q only
    hr[base + j]      = (bf16_t)((x1*cs - x2*sn) * sc);
    hr[base + j + 32] = (bf16_t)((x2*cs + x1*sn) * sc);
  }
  for (int d = t; d < 64; d += 256)
    Vt[(size_t)(b*64 + d) * SEQ + s] = hr[2112 + d];
}

// ---------------- 5. flash attention (causal, MQA) ----------------
// 8 waves, BQ=128, BKV=128. Mirror-paired q-tiles (qb=p, 15-p) -> 17 KV tiles per
// block, uniform (kills tail imbalance). Double-buffered K/V with reg-prefetch
// (T14 async-stage: global latency hides under QK+softmax). setprio on MFMA (T5).
template<bool MASK>
__device__ __forceinline__ void attn_qk_sm(
    const bf16_t* __restrict__ Qs, const bf16_t* __restrict__ Ks,
    bf16_t* __restrict__ Ps,
    f32x4 (&accO)[4], float (&m_run)[4], float (&l_run)[4],
    int w, int lr, int lq, int q0, int j0)
{
  const f32x4 z4 = {0.f,0.f,0.f,0.f};
  f32x4 accS[8];
#pragma unroll
  for (int i = 0; i < 8; i++) accS[i] = z4;
  bf16x8 aq[2];
#pragma unroll
  for (int kt = 0; kt < 2; kt++)
    aq[kt] = *(const bf16x8*)&Qs[(w*16 + lr)*72 + kt*32 + lq*8];
  __builtin_amdgcn_s_setprio(1);
#pragma unroll
  for (int nt = 0; nt < 8; nt++)
#pragma unroll
    for (int kt = 0; kt < 2; kt++) {
      bf16x8 bk = *(const bf16x8*)&Ks[(nt*16 + lr)*72 + kt*32 + lq*8];
      accS[nt] = __builtin_amdgcn_mfma_f32_16x16x32_bf16(aq[kt], bk, accS[nt], 0, 0, 0);
    }
  __builtin_amdgcn_s_setprio(0);
  if (MASK) {
    const int rg0 = q0 + w*16 + lq*4;
#pragma unroll
    for (int nt = 0; nt < 8; nt++) {
      const int cg = j0 + nt*16 + lr;
#pragma unroll
      for (int r = 0; r < 4; r++)
        if (cg > rg0 + r) accS[nt][r] = -3.0e38f;
    }
  }
  float al[4];
#pragma unroll
  for (int r = 0; r < 4; r++) {
    float m = accS[0][r];
#pragma unroll
    for (int nt = 1; nt < 8; nt++) m = fmaxf(m, accS[nt][r]);
    m = fmaxf(m, __shfl_xor(m, 1)); m = fmaxf(m, __shfl_xor(m, 2));
    m = fmaxf(m, __shfl_xor(m, 4)); m = fmaxf(m, __shfl_xor(m, 8));
    const float nm = fmaxf(m_run[r], m);
    al[r] = __expf(m_run[r] - nm);
    m_run[r] = nm;
  }
#pragma unroll
  for (int nt = 0; nt < 8; nt++)
#pragma unroll
    for (int r = 0; r < 4; r++)
      accS[nt][r] = __expf(accS[nt][r] - m_run[r]);
#pragma unroll
  for (int r = 0; r < 4; r++) {
    float sum = 0.f;
#pragma unroll
    for (int nt = 0; nt < 8; nt++) sum += accS[nt][r];
    sum += __shfl_xor(sum, 1); sum += __shfl_xor(sum, 2);
    sum += __shfl_xor(sum, 4); sum += __shfl_xor(sum, 8);
    l_run[r] = l_run[r]*al[r] + sum;
  }
#pragma unroll
  for (int nt = 0; nt < 4; nt++)
#pragma unroll
    for (int r = 0; r < 4; r++) accO[nt][r] *= al[r];
  // P: C-layout regs -> LDS (A-operand layout for PV)
#pragma unroll
  for (int nt = 0; nt < 8; nt++)
#pragma unroll
    for (int r = 0; r < 4; r++)
      Ps[(w*16 + lq*4 + r)*136 + nt*16 + lr] = (bf16_t)accS[nt][r];
}

__device__ __forceinline__ void attn_pv(
    const bf16_t* __restrict__ Ps, const bf16_t* __restrict__ Vts,
    f32x4 (&accO)[4], int w, int lr, int lq)
{
  __builtin_amdgcn_s_setprio(1);
#pragma unroll
  for (int kt = 0; kt < 4; kt++) {
    bf16x8 ap = *(const bf16x8*)&Ps[(w*16 + lr)*136 + kt*32 + lq*8];
#pragma unroll
    for (int nt = 0; nt < 4; nt++) {
      bf16x8 bv = *(const bf16x8*)&Vts[(nt*16 + lr)*136 + kt*32 + lq*8];
      accO[nt] = __builtin_amdgcn_mfma_f32_16x16x32_bf16(ap, bv, accO[nt], 0, 0, 0);
    }
  }
  __builtin_amdgcn_s_setprio(0);
}

// grid (8, NHEADS, NB), 512 threads
__global__ __launch_bounds__(512, 2) void attn_kernel(const bf16_t* __restrict__ H,
                                                      const bf16_t* __restrict__ Vt,
                                                      bf16_t* __restrict__ AttnOut)
{
  __shared__ __align__(16) bf16_t Qs[128*72];
  __shared__ __align__(16) bf16_t Ks[2][128*72];
  __shared__ __align__(16) bf16_t Vts[2][64*136];
  __shared__ __align__(16) bf16_t Ps[128*136];
  const int t = threadIdx.x, l = t & 63, w = t >> 6, lr = l & 15, lq = l >> 4;
  const int pid = blockIdx.x, head = blockIdx.y, b = blockIdx.z;
  const size_t hbase = (size_t)(b * SEQ) * HC;
  const int kch = (t & 7) << 3, vch = (t & 15) << 3;

  for (int half = 0; half < 2; half++) {
    const int qb = half ? (15 - pid) : pid;
    const int q0 = qb << 7;
    const int ntiles = qb + 1;
    // ---- prologue: stage Q + KV tile 0 ----
    bf16x8 kr[2], vr[2], qr[2];
#pragma unroll
    for (int i = 0; i < 2; i++) {
      const int id = t + i*512;
      qr[i] = *(const bf16x8*)&H[hbase + (size_t)(q0 + (id>>3)) * HC + head*64 + ((id&7)<<3)];
      kr[i] = *(const bf16x8*)&H[hbase + (size_t)(id>>3) * HC + 2048 + kch];
      vr[i] = *(const bf16x8*)&Vt[(size_t)(b*64 + (id>>4)) * SEQ + vch];
    }
#pragma unroll
    for (int i = 0; i < 2; i++) {
      const int id = t + i*512;
      *(bf16x8*)&Qs[(id>>3)*72 + ((id&7)<<3)] = qr[i];
      *(bf16x8*)&Ks[0][(id>>3)*72 + kch] = kr[i];
      *(bf16x8*)&Vts[0][(id>>4)*136 + vch] = vr[i];
    }
    f32x4 accO[4];
    const f32x4 z4 = {0.f,0.f,0.f,0.f};
#pragma unroll
    for (int i = 0; i < 4; i++) accO[i] = z4;
    float m_run[4], l_run[4];
#pragma unroll
    for (int r = 0; r < 4; r++) { m_run[r] = -3.0e38f; l_run[r] = 0.f; }
    __syncthreads();

    for (int tile = 0; tile < ntiles; tile++) {
      const int cur = tile & 1;
      const bool last = (tile == ntiles - 1);
      if (!last) {      // T14: issue next tile's K/V loads early
        const int j1 = (tile + 1) << 7;
#pragma unroll
        for (int i = 0; i < 2; i++) {
          const int id = t + i*512;
          kr[i] = *(const bf16x8*)&H[hbase + (size_t)(j1 + (id>>3)) * HC + 2048 + kch];
          vr[i] = *(const bf16x8*)&Vt[(size_t)(b*64 + (id>>4)) * SEQ + j1 + vch];
        }
      }
      if (last)
        attn_qk_sm<true >(Qs, Ks[cur], Ps, accO, m_run, l_run, w, lr, lq, q0, tile<<7);
      else
        attn_qk_sm<false>(Qs, Ks[cur], Ps, accO, m_run, l_run, w, lr, lq, q0, tile<<7);
      if (!last) {      // write-late into the other buffer (safe: its last readers
                        //  finished before the previous tile's trailing barrier)
#pragma unroll
        for (int i = 0; i < 2; i++) {
          const int id = t + i*512;
          *(bf16x8*)&Ks[cur^1][(id>>3)*72 + kch] = kr[i];
          *(bf16x8*)&Vts[cur^1][(id>>4)*136 + vch] = vr[i];
        }
      }
      __syncthreads();
      attn_pv(Ps, Vts[cur], accO, w, lr, lq);
      __syncthreads();
    }
    float inv_l[4];
#pragma unroll
    for (int r = 0; r < 4; r++) inv_l[r] = 1.f / l_run[r];
#pragma unroll
    for (int nt = 0; nt < 4; nt++)
#pragma unroll
      for (int r = 0; r < 4; r++)
        AttnOut[(size_t)(b*SEQ + q0 + w*16 + lq*4 + r) * DIMN + head*64 + nt*16 + lr]
            = (bf16_t)(accO[nt][r] * inv_l[r]);
  }
}

// ---------------- launcher ----------------
extern "C" void kernel_launch(void* const* d_in, const int* in_sizes, int n_in,
                              void* d_out, int out_size, void* d_ws, size_t ws_size,
                              hipStream_t stream)
{
  const float* x     = (const float*)d_in[0];
  const float* W_in  = (const float*)d_in[1];
  const float* W_out = (const float*)d_in[2];
  const float* gamma = (const float*)d_in[3];
  const float* beta  = (const float*)d_in[4];
  float* out = (float*)d_out;

  char* ws = (char*)d_ws;
  bf16_t* xnb   = (bf16_t*)(ws);                 // 16,777,216
  bf16_t* h     = (bf16_t*)(ws + 16777216);      // 84,934,656
  bf16_t* WinT  = (bf16_t*)(ws + 101711872);     // 42,467,328  [HC][DIMN]
  bf16_t* WoutT = (bf16_t*)(ws + 144179200);     // 41,943,040  [DIMN][OI]
  bf16_t* Vt    = (bf16_t*)(ws + 186122240);     //    524,288  [NB][64][SEQ]
  bf16_t* attn  = (bf16_t*)(ws + 186646528);     // 16,777,216  [NROWS][DIMN]

  ln_kernel<<<NROWS, 256, 0, stream>>>(x, gamma, beta, xnb);
  tcast_kernel<<<dim3(HC/32, DIMN/128), 256, 0, stream>>>(W_in, WINLD, WinT, DIMN);
  tcast_kernel<<<dim3(DIMN/32, OI/128), 256, 0, stream>>>(W_out, DIMN, WoutT, OI);
  gemm8p<256,256,DIMN,0><<<656, 512, 0, stream>>>(xnb, nullptr, WinT, nullptr, h, nullptr);
  rope_kernel<<<NROWS, 256, 0, stream>>>(h, Vt);
  attn_kernel<<<dim3(8, NHEADS, NB), 512, 0, stream>>>(h, Vt, attn);
  gemm8p<128,256,OI,1><<<256, 512, 0, stream>>>(attn, h, WoutT, xnb, nullptr, out);
}

// Round 4
// 754.424 us; speedup vs baseline: 1.2196x; 1.0568x over previous
//
#include <hip/hip_runtime.h>
#include <cstdint>

// ---------------- problem constants ----------------
#define NB     2
#define SEQ    2048
#define DIMN   2048
#define NROWS  (NB*SEQ)        // 4096
#define NHEADS 32
#define DHEAD  64
#define FFN    8192
#define HC     10368           // used cols of h: 2048 q | 64 k | 64 v | 8192 ffn
#define WINLD  18560           // W_in full leading dim
#define OI     10240           // W_out rows (attn 2048 | ffn 8192)

typedef __bf16 bf16_t;
typedef bf16_t bf16x8 __attribute__((ext_vector_type(8)));
typedef bf16_t bf16x4 __attribute__((ext_vector_type(4)));
typedef bf16_t bf16x2 __attribute__((ext_vector_type(2)));
typedef float  f32x4  __attribute__((ext_vector_type(4)));

typedef const uint32_t __attribute__((address_space(1)))* as1p;
typedef uint32_t __attribute__((address_space(3)))* as3p;

// async global->LDS, 16B/lane. LDS dest = wave-uniform base + lane*16 (guide §5).
__device__ __forceinline__ void load_lds16(const void* g, void* l) {
  __builtin_amdgcn_global_load_lds(
      reinterpret_cast<as1p>(reinterpret_cast<uintptr_t>(g)),
      reinterpret_cast<as3p>(reinterpret_cast<uintptr_t>(l)),
      16, 0, 0);
}

// ---------------- 1. LayerNorm -> bf16 ----------------
__global__ __launch_bounds__(256) void ln_kernel(const float* __restrict__ x,
                                                 const float* __restrict__ gamma,
                                                 const float* __restrict__ beta,
                                                 bf16_t* __restrict__ xnb)
{
  const int row = blockIdx.x;
  const int t = threadIdx.x;
  const float4* xr = (const float4*)(x + (size_t)row * DIMN);
  float4 v0 = xr[t], v1 = xr[t + 256];
  float s  = v0.x+v0.y+v0.z+v0.w + v1.x+v1.y+v1.z+v1.w;
  float ss = v0.x*v0.x+v0.y*v0.y+v0.z*v0.z+v0.w*v0.w
           + v1.x*v1.x+v1.y*v1.y+v1.z*v1.z+v1.w*v1.w;
#pragma unroll
  for (int off = 32; off; off >>= 1) { s += __shfl_xor(s, off); ss += __shfl_xor(ss, off); }
  __shared__ float red[8];
  const int w = t >> 6;
  if ((t & 63) == 0) { red[w] = s; red[w + 4] = ss; }
  __syncthreads();
  s  = red[0]+red[1]+red[2]+red[3];
  ss = red[4]+red[5]+red[6]+red[7];
  const float mu   = s * (1.f/DIMN);
  const float var  = ss * (1.f/DIMN) - mu*mu;
  const float rstd = rsqrtf(var + 1e-5f);
  const float4* g4 = (const float4*)gamma;
  const float4* b4 = (const float4*)beta;
  float4 ga0 = g4[t], ga1 = g4[t+256], be0 = b4[t], be1 = b4[t+256];
  float4 y0, y1;
  y0.x = (v0.x-mu)*rstd*ga0.x + be0.x;  y0.y = (v0.y-mu)*rstd*ga0.y + be0.y;
  y0.z = (v0.z-mu)*rstd*ga0.z + be0.z;  y0.w = (v0.w-mu)*rstd*ga0.w + be0.w;
  y1.x = (v1.x-mu)*rstd*ga1.x + be1.x;  y1.y = (v1.y-mu)*rstd*ga1.y + be1.y;
  y1.z = (v1.z-mu)*rstd*ga1.z + be1.z;  y1.w = (v1.w-mu)*rstd*ga1.w + be1.w;
  bf16_t* xo = xnb + (size_t)row * DIMN;
  bf16x4 o0 = {(bf16_t)y0.x, (bf16_t)y0.y, (bf16_t)y0.z, (bf16_t)y0.w};
  bf16x4 o1 = {(bf16_t)y1.x, (bf16_t)y1.y, (bf16_t)y1.z, (bf16_t)y1.w};
  *(bf16x4*)(xo + t*4)        = o0;
  *(bf16x4*)(xo + (t+256)*4)  = o1;
}

// ---------------- 2. transpose-cast fp32 -> bf16 (out[r][c] = in[c][r]) ----------------
__global__ __launch_bounds__(256) void tcast_kernel(const float* __restrict__ in, int ld_in,
                                                    bf16_t* __restrict__ out, int out_cols)
{
  __shared__ float tile[128][33];
  const int t = threadIdx.x;
  const int ic0 = blockIdx.x * 32;    // in col block = out row block
  const int ir0 = blockIdx.y * 128;   // in row block = out col block
#pragma unroll
  for (int k = 0; k < 16; k++) {
    const int idx = k*256 + t, row = idx >> 5, col = idx & 31;
    tile[row][col] = in[(size_t)(ir0 + row) * ld_in + ic0 + col];
  }
  __syncthreads();
#pragma unroll
  for (int k = 0; k < 8; k++) {
    const int idx = k*256 + t, r = idx >> 6, cp = idx & 63;
    bf16x2 v = {(bf16_t)tile[cp*2][r], (bf16_t)tile[cp*2 + 1][r]};
    *(bf16x2*)&out[(size_t)(ic0 + r) * out_cols + ir0 + cp*2] = v;
  }
}

// ---------------- 3. 8-phase 256-class GEMM (guide §5 template, plain HIP) ----------------
// R2: A-fragment register-hold across (QM,0)->(QM,1) phase couples. The even phase
// of each couple reuses af[] read in the odd phase: -33% LDS read traffic (gemm1),
// -25% (gemm2). The LDS pipe (8 waves x 12 ds_read_b128/phase ~= 770-1150 cy/CU)
// was the binding constraint vs 621 cy MFMA. No sync/race-structure change.
#define BW_NONE ((void)0)
#define BW_VM   asm volatile("s_waitcnt vmcnt(%0)" :: "n"(VM))
#define BW_V0   asm volatile("s_waitcnt vmcnt(0)")

template<int BM, int BN, int KTOT, int OP>
__global__ __launch_bounds__(512, 2) void gemm8p(
    const bf16_t* __restrict__ A0p, const bf16_t* __restrict__ A1p,
    const bf16_t* __restrict__ Btp, const bf16_t* __restrict__ Res,
    bf16_t* __restrict__ Cb, float* __restrict__ Cf)
{
  constexpr int NT    = KTOT / 64;       // K tiles
  constexpr int NP    = NT / 2;          // tile pairs
  constexpr int MR    = BM / 64;         // m-frags per phase per wave
  constexpr int NRr   = BN / 128;        // n-frags per phase per wave
  constexpr int ALPT  = BM / 128;        // A loads/thread per half-tile
  constexpr int BLPT  = BN / 128;
  constexpr int VM    = ALPT + BLPT;     // steady-state vmcnt
  constexpr int AHALF = (BM/2)*64;       // elements
  constexpr int BHALF = (BN/2)*64;
  constexpr int ABUF  = BM*64;
  constexpr int BUFSZ = ABUF + BN*64;
  constexpr int BLD   = OP ? OI : DIMN;
  constexpr int CPX   = OP ? 32 : 82;    // grid/8 for XCD swizzle
  __shared__ __align__(16) bf16_t lds[2*BUFSZ];

  const int t = threadIdx.x;
  const int l = t & 63, w = t >> 6;
  const int wm2 = w >> 2, wn2 = w & 3;
  const int lr = l & 15, lq = l >> 4;

  const int id  = blockIdx.x;
  const int swz = (id & 7) * CPX + (id >> 3);
  int m0, n0;
  if (OP == 0) {                       // 16 m-tiles x 41 n-tiles (last clamped)
    m0 = (swz & 15) << 8;
    n0 = (swz >> 4) << 8;
    if (n0 > HC - 256) n0 = HC - 256;
  } else {                             // 32 m-tiles x 8 n-tiles
    m0 = (swz & 31) << 7;
    n0 = (swz >> 5) << 8;
  }

  const int rsw = (w << 3) | (l >> 3);
  const int csw = (((l & 7) ^ ((l >> 3) & 7)) << 3);
  const int axor[2] = { ((lq ^ (lr & 7)) << 3), (((4 + lq) ^ (lr & 7)) << 3) };
  const int arow = wm2*(BM/4) + lr;
  const int brow = wn2*(BN/8) + lr;

  auto stA = [&](int buf, int half, int kt) {
    const int k0 = kt * 64;
#pragma unroll
    for (int c = 0; c < ALPT; c++) {
      const int gr = m0 + half*(BM/2) + c*64 + rsw;
      const bf16_t* src;
      if (OP == 0 || k0 < DIMN) src = A0p + (size_t)gr * DIMN + k0 + csw;
      else                      src = A1p + (size_t)gr * HC + 2176 + (k0 - DIMN) + csw;
      load_lds16(src, lds + buf*BUFSZ + half*AHALF + c*4096 + (w << 9));
    }
  };
  auto stB = [&](int buf, int half, int kt) {
    const int k0 = kt * 64;
#pragma unroll
    for (int c = 0; c < BLPT; c++) {
      const int gr = n0 + half*(BN/2) + c*64 + rsw;
      load_lds16(Btp + (size_t)gr * BLD + k0 + csw,
                 lds + buf*BUFSZ + ABUF + half*BHALF + c*4096 + (w << 9));
    }
  };

  f32x4 acc[2][2][MR][NRr];
  const f32x4 z4 = {0.f,0.f,0.f,0.f};
#pragma unroll
  for (int qm = 0; qm < 2; qm++)
#pragma unroll
    for (int qn = 0; qn < 2; qn++)
#pragma unroll
      for (int i = 0; i < MR; i++)
#pragma unroll
        for (int j = 0; j < NRr; j++) acc[qm][qn][i][j] = z4;

  bf16x8 af[MR][2];   // A-fragments, held across (QM,0)->(QM,1) phase couples

  stA(0,0,0); stA(0,1,0); stB(0,0,0); stB(0,1,0);
  stA(1,0,1); stB(1,0,1);
  BW_VM;
  __builtin_amdgcn_sched_barrier(0);
  __builtin_amdgcn_s_barrier();
  __builtin_amdgcn_sched_barrier(0);

// RA=1: (re)load af from LDS (odd phases / new QM or buffer). RA=0: reuse regs.
#define PHASE(BUF, QM, QN, RA, STAGE, BWAIT)                                  \
  {                                                                           \
    if (RA) {                                                                 \
      _Pragma("unroll")                                                       \
      for (int i_ = 0; i_ < MR; i_++)                                         \
        _Pragma("unroll")                                                     \
        for (int kk_ = 0; kk_ < 2; kk_++)                                     \
          af[i_][kk_] = *(const bf16x8*)&lds[(BUF)*BUFSZ + (QM)*AHALF         \
                          + (arow + i_*16)*64 + axor[kk_]];                   \
    }                                                                         \
    bf16x8 bfr[NRr][2];                                                       \
    _Pragma("unroll")                                                         \
    for (int j_ = 0; j_ < NRr; j_++)                                          \
      _Pragma("unroll")                                                       \
      for (int kk_ = 0; kk_ < 2; kk_++)                                       \
        bfr[j_][kk_] = *(const bf16x8*)&lds[(BUF)*BUFSZ + ABUF + (QN)*BHALF   \
                        + (brow + j_*16)*64 + axor[kk_]];                     \
    STAGE;                                                                    \
    __builtin_amdgcn_s_barrier();                                             \
    __builtin_amdgcn_sched_barrier(0);                                        \
    __builtin_amdgcn_s_setprio(1);                                            \
    _Pragma("unroll")                                                         \
    for (int i_ = 0; i_ < MR; i_++)                                           \
      _Pragma("unroll")                                                       \
      for (int j_ = 0; j_ < NRr; j_++)                                        \
        _Pragma("unroll")                                                     \
        for (int kk_ = 0; kk_ < 2; kk_++)                                     \
          acc[QM][QN][i_][j_] = __builtin_amdgcn_mfma_f32_16x16x32_bf16(      \
              af[i_][kk_], bfr[j_][kk_], acc[QM][QN][i_][j_], 0, 0, 0);       \
    __builtin_amdgcn_s_setprio(0);                                            \
    BWAIT;                                                                    \
    __builtin_amdgcn_s_barrier();                                             \
    __builtin_amdgcn_sched_barrier(0);                                        \
  }

  for (int it = 0; it < NP-1; it++) {
    const int e = 2*it, o = e+1;
    PHASE(0,0,0, 1, stA(1,1,o),   BW_NONE)
    PHASE(0,0,1, 0, stB(1,1,o),   BW_NONE)
    PHASE(0,1,0, 1, stA(0,0,e+2), BW_NONE)
    PHASE(0,1,1, 0, stB(0,0,e+2), BW_VM)
    PHASE(1,0,0, 1, stA(0,1,e+2), BW_NONE)
    PHASE(1,0,1, 0, stB(0,1,e+2), BW_NONE)
    PHASE(1,1,0, 1, stA(1,0,o+2), BW_NONE)
    PHASE(1,1,1, 0, stB(1,0,o+2), BW_VM)
  }
  {
    const int o = NT-1;
    PHASE(0,0,0, 1, stA(1,1,o), BW_NONE)
    PHASE(0,0,1, 0, stB(1,1,o), BW_NONE)
    PHASE(0,1,0, 1, BW_NONE,    BW_NONE)
    PHASE(0,1,1, 0, BW_NONE,    BW_V0)
    PHASE(1,0,0, 1, BW_NONE,    BW_NONE)
    PHASE(1,0,1, 0, BW_NONE,    BW_NONE)
    PHASE(1,1,0, 1, BW_NONE,    BW_NONE)
    PHASE(1,1,1, 0, BW_NONE,    BW_NONE)
  }
#undef PHASE

#pragma unroll
  for (int qm = 0; qm < 2; qm++)
#pragma unroll
    for (int qn = 0; qn < 2; qn++)
#pragma unroll
      for (int i = 0; i < MR; i++)
#pragma unroll
        for (int j = 0; j < NRr; j++) {
          const int row = m0 + qm*(BM/2) + wm2*(BM/4) + i*16 + lq*4;
          const int col = n0 + qn*(BN/2) + wn2*(BN/8) + j*16 + lr;
#pragma unroll
          for (int r = 0; r < 4; r++) {
            if (OP == 0) {
              Cb[(size_t)(row + r) * HC + col] = (bf16_t)acc[qm][qn][i][j][r];
            } else {
              const size_t idx = (size_t)(row + r) * DIMN + col;
              Cf[idx] = acc[qm][qn][i][j][r] + (float)Res[idx];
            }
          }
        }
}

// ---------------- 4. RoPE in-place on q,k of h; extract V^T ----------------
__global__ __launch_bounds__(256) void rope_kernel(bf16_t* __restrict__ H, bf16_t* __restrict__ Vt)
{
  const int row = blockIdx.x;          // b*SEQ + s
  const int s = row & (SEQ - 1);
  const int b = row >> 11;
  bf16_t* hr = H + (size_t)row * HC;
  const int t = threadIdx.x;
  for (int task = t; task < 1056; task += 256) {
    const int hd = task >> 5, j = task & 31;
    const int base = (hd < 32) ? hd*64 : 2048;
    const float inv = exp2f(-(float)j * 0.41524101186092437f);
    const float ang = (float)s * inv;
    float sn, cs;
    sincosf(ang, &sn, &cs);
    const float x1 = (float)hr[base + j], x2 = (float)hr[base + j + 32];
    const float sc = (hd < 32) ? 0.125f : 1.0f;   // SCALE on q only
    hr[base + j]      = (bf16_t)((x1*cs - x2*sn) * sc);
    hr[base + j + 32] = (bf16_t)((x2*cs + x1*sn) * sc);
  }
  for (int d = t; d < 64; d += 256)
    Vt[(size_t)(b*64 + d) * SEQ + s] = hr[2112 + d];
}

// ---------------- 5. flash attention (causal, MQA) ----------------
// 8 waves, BQ=128, BKV=128. Mirror-paired q-tiles (qb=p, 15-p) -> 17 KV tiles per
// block, uniform (kills tail imbalance). Double-buffered K/V with reg-prefetch
// (T14 async-stage: global latency hides under QK+softmax). setprio on MFMA (T5).
template<bool MASK>
__device__ __forceinline__ void attn_qk_sm(
    const bf16_t* __restrict__ Qs, const bf16_t* __restrict__ Ks,
    bf16_t* __restrict__ Ps,
    f32x4 (&accO)[4], float (&m_run)[4], float (&l_run)[4],
    int w, int lr, int lq, int q0, int j0)
{
  const f32x4 z4 = {0.f,0.f,0.f,0.f};
  f32x4 accS[8];
#pragma unroll
  for (int i = 0; i < 8; i++) accS[i] = z4;
  bf16x8 aq[2];
#pragma unroll
  for (int kt = 0; kt < 2; kt++)
    aq[kt] = *(const bf16x8*)&Qs[(w*16 + lr)*72 + kt*32 + lq*8];
  __builtin_amdgcn_s_setprio(1);
#pragma unroll
  for (int nt = 0; nt < 8; nt++)
#pragma unroll
    for (int kt = 0; kt < 2; kt++) {
      bf16x8 bk = *(const bf16x8*)&Ks[(nt*16 + lr)*72 + kt*32 + lq*8];
      accS[nt] = __builtin_amdgcn_mfma_f32_16x16x32_bf16(aq[kt], bk, accS[nt], 0, 0, 0);
    }
  __builtin_amdgcn_s_setprio(0);
  if (MASK) {
    const int rg0 = q0 + w*16 + lq*4;
#pragma unroll
    for (int nt = 0; nt < 8; nt++) {
      const int cg = j0 + nt*16 + lr;
#pragma unroll
      for (int r = 0; r < 4; r++)
        if (cg > rg0 + r) accS[nt][r] = -3.0e38f;
    }
  }
  float al[4];
#pragma unroll
  for (int r = 0; r < 4; r++) {
    float m = accS[0][r];
#pragma unroll
    for (int nt = 1; nt < 8; nt++) m = fmaxf(m, accS[nt][r]);
    m = fmaxf(m, __shfl_xor(m, 1)); m = fmaxf(m, __shfl_xor(m, 2));
    m = fmaxf(m, __shfl_xor(m, 4)); m = fmaxf(m, __shfl_xor(m, 8));
    const float nm = fmaxf(m_run[r], m);
    al[r] = __expf(m_run[r] - nm);
    m_run[r] = nm;
  }
#pragma unroll
  for (int nt = 0; nt < 8; nt++)
#pragma unroll
    for (int r = 0; r < 4; r++)
      accS[nt][r] = __expf(accS[nt][r] - m_run[r]);
#pragma unroll
  for (int r = 0; r < 4; r++) {
    float sum = 0.f;
#pragma unroll
    for (int nt = 0; nt < 8; nt++) sum += accS[nt][r];
    sum += __shfl_xor(sum, 1); sum += __shfl_xor(sum, 2);
    sum += __shfl_xor(sum, 4); sum += __shfl_xor(sum, 8);
    l_run[r] = l_run[r]*al[r] + sum;
  }
#pragma unroll
  for (int nt = 0; nt < 4; nt++)
#pragma unroll
    for (int r = 0; r < 4; r++) accO[nt][r] *= al[r];
  // P: C-layout regs -> LDS (A-operand layout for PV)
#pragma unroll
  for (int nt = 0; nt < 8; nt++)
#pragma unroll
    for (int r = 0; r < 4; r++)
      Ps[(w*16 + lq*4 + r)*136 + nt*16 + lr] = (bf16_t)accS[nt][r];
}

__device__ __forceinline__ void attn_pv(
    const bf16_t* __restrict__ Ps, const bf16_t* __restrict__ Vts,
    f32x4 (&accO)[4], int w, int lr, int lq)
{
  __builtin_amdgcn_s_setprio(1);
#pragma unroll
  for (int kt = 0; kt < 4; kt++) {
    bf16x8 ap = *(const bf16x8*)&Ps[(w*16 + lr)*136 + kt*32 + lq*8];
#pragma unroll
    for (int nt = 0; nt < 4; nt++) {
      bf16x8 bv = *(const bf16x8*)&Vts[(nt*16 + lr)*136 + kt*32 + lq*8];
      accO[nt] = __builtin_amdgcn_mfma_f32_16x16x32_bf16(ap, bv, accO[nt], 0, 0, 0);
    }
  }
  __builtin_amdgcn_s_setprio(0);
}

// grid (8, NHEADS, NB), 512 threads
__global__ __launch_bounds__(512, 2) void attn_kernel(const bf16_t* __restrict__ H,
                                                      const bf16_t* __restrict__ Vt,
                                                      bf16_t* __restrict__ AttnOut)
{
  __shared__ __align__(16) bf16_t Qs[128*72];
  __shared__ __align__(16) bf16_t Ks[2][128*72];
  __shared__ __align__(16) bf16_t Vts[2][64*136];
  __shared__ __align__(16) bf16_t Ps[128*136];
  const int t = threadIdx.x, l = t & 63, w = t >> 6, lr = l & 15, lq = l >> 4;
  const int pid = blockIdx.x, head = blockIdx.y, b = blockIdx.z;
  const size_t hbase = (size_t)(b * SEQ) * HC;
  const int kch = (t & 7) << 3, vch = (t & 15) << 3;

  for (int half = 0; half < 2; half++) {
    const int qb = half ? (15 - pid) : pid;
    const int q0 = qb << 7;
    const int ntiles = qb + 1;
    // ---- prologue: stage Q + KV tile 0 ----
    bf16x8 kr[2], vr[2], qr[2];
#pragma unroll
    for (int i = 0; i < 2; i++) {
      const int id = t + i*512;
      qr[i] = *(const bf16x8*)&H[hbase + (size_t)(q0 + (id>>3)) * HC + head*64 + ((id&7)<<3)];
      kr[i] = *(const bf16x8*)&H[hbase + (size_t)(id>>3) * HC + 2048 + kch];
      vr[i] = *(const bf16x8*)&Vt[(size_t)(b*64 + (id>>4)) * SEQ + vch];
    }
#pragma unroll
    for (int i = 0; i < 2; i++) {
      const int id = t + i*512;
      *(bf16x8*)&Qs[(id>>3)*72 + ((id&7)<<3)] = qr[i];
      *(bf16x8*)&Ks[0][(id>>3)*72 + kch] = kr[i];
      *(bf16x8*)&Vts[0][(id>>4)*136 + vch] = vr[i];
    }
    f32x4 accO[4];
    const f32x4 z4 = {0.f,0.f,0.f,0.f};
#pragma unroll
    for (int i = 0; i < 4; i++) accO[i] = z4;
    float m_run[4], l_run[4];
#pragma unroll
    for (int r = 0; r < 4; r++) { m_run[r] = -3.0e38f; l_run[r] = 0.f; }
    __syncthreads();

    for (int tile = 0; tile < ntiles; tile++) {
      const int cur = tile & 1;
      const bool last = (tile == ntiles - 1);
      if (!last) {      // T14: issue next tile's K/V loads early
        const int j1 = (tile + 1) << 7;
#pragma unroll
        for (int i = 0; i < 2; i++) {
          const int id = t + i*512;
          kr[i] = *(const bf16x8*)&H[hbase + (size_t)(j1 + (id>>3)) * HC + 2048 + kch];
          vr[i] = *(const bf16x8*)&Vt[(size_t)(b*64 + (id>>4)) * SEQ + j1 + vch];
        }
      }
      if (last)
        attn_qk_sm<true >(Qs, Ks[cur], Ps, accO, m_run, l_run, w, lr, lq, q0, tile<<7);
      else
        attn_qk_sm<false>(Qs, Ks[cur], Ps, accO, m_run, l_run, w, lr, lq, q0, tile<<7);
      if (!last) {      // write-late into the other buffer (safe: its last readers
                        //  finished before the previous tile's trailing barrier)
#pragma unroll
        for (int i = 0; i < 2; i++) {
          const int id = t + i*512;
          *(bf16x8*)&Ks[cur^1][(id>>3)*72 + kch] = kr[i];
          *(bf16x8*)&Vts[cur^1][(id>>4)*136 + vch] = vr[i];
        }
      }
      __syncthreads();
      attn_pv(Ps, Vts[cur], accO, w, lr, lq);
      __syncthreads();
    }
    float inv_l[4];
#pragma unroll
    for (int r = 0; r < 4; r++) inv_l[r] = 1.f / l_run[r];
#pragma unroll
    for (int nt = 0; nt < 4; nt++)
#pragma unroll
      for (int r = 0; r < 4; r++)
        AttnOut[(size_t)(b*SEQ + q0 + w*16 + lq*4 + r) * DIMN + head*64 + nt*16 + lr]
            = (bf16_t)(accO[nt][r] * inv_l[r]);
  }
}

// ---------------- launcher ----------------
extern "C" void kernel_launch(void* const* d_in, const int* in_sizes, int n_in,
                              void* d_out, int out_size, void* d_ws, size_t ws_size,
                              hipStream_t stream)
{
  const float* x     = (const float*)d_in[0];
  const float* W_in  = (const float*)d_in[1];
  const float* W_out = (const float*)d_in[2];
  const float* gamma = (const float*)d_in[3];
  const float* beta  = (const float*)d_in[4];
  float* out = (float*)d_out;

  char* ws = (char*)d_ws;
  bf16_t* xnb   = (bf16_t*)(ws);                 // 16,777,216
  bf16_t* h     = (bf16_t*)(ws + 16777216);      // 84,934,656
  bf16_t* WinT  = (bf16_t*)(ws + 101711872);     // 42,467,328  [HC][DIMN]
  bf16_t* WoutT = (bf16_t*)(ws + 144179200);     // 41,943,040  [DIMN][OI]
  bf16_t* Vt    = (bf16_t*)(ws + 186122240);     //    524,288  [NB][64][SEQ]
  bf16_t* attn  = (bf16_t*)(ws + 186646528);     // 16,777,216  [NROWS][DIMN]

  ln_kernel<<<NROWS, 256, 0, stream>>>(x, gamma, beta, xnb);
  tcast_kernel<<<dim3(HC/32, DIMN/128), 256, 0, stream>>>(W_in, WINLD, WinT, DIMN);
  tcast_kernel<<<dim3(DIMN/32, OI/128), 256, 0, stream>>>(W_out, DIMN, WoutT, OI);
  gemm8p<256,256,DIMN,0><<<656, 512, 0, stream>>>(xnb, nullptr, WinT, nullptr, h, nullptr);
  rope_kernel<<<NROWS, 256, 0, stream>>>(h, Vt);
  attn_kernel<<<dim3(8, NHEADS, NB), 512, 0, stream>>>(h, Vt, attn);
  gemm8p<128,256,OI,1><<<256, 512, 0, stream>>>(attn, h, WoutT, xnb, nullptr, out);
}